// Round 1
// baseline (587.714 us; speedup 1.0000x reference)
//
#include <hip/hip_runtime.h>
#include <cstdint>

typedef unsigned short u16;
typedef u16 u16x8 __attribute__((ext_vector_type(8)));
typedef __bf16 bf16x8 __attribute__((ext_vector_type(8)));
typedef float f32x4 __attribute__((ext_vector_type(4)));

#define DEV static __device__ __forceinline__

// problem constants
constexpr int NT = 8192;         // tokens
constexpr int NP = NT * 2;       // 16384 (token, k) pairs
constexpr int NE = 8;
constexpr int DM = 1024;
constexpr int DF = 2048;
constexpr int MAXS = 17408;      // 16384 + 8*128 slack for 128-alignment padding

DEV u16 f2bf(float f) {          // RTNE float -> bf16 bits
  uint32_t u = __builtin_bit_cast(uint32_t, f);
  u += 0x7fffu + ((u >> 16) & 1u);
  return (u16)(u >> 16);
}

DEV void gload16(const void* g, void* l) {
  __builtin_amdgcn_global_load_lds((const __attribute__((address_space(1))) void*)g,
                                   (__attribute__((address_space(3))) void*)l, 16, 0, 0);
}

// ---- routing ----
// meta[0..7]=counts, meta[8..15]=cursor, meta[16..24]=padded offsets (+total)
__global__ void k_init(int* meta, int* slot_token) {
  const int i = blockIdx.x * 256 + threadIdx.x;
  if (i < 32) meta[i] = 0;
  if (i < MAXS) slot_token[i] = -1;
}

__global__ void k_count(const int* __restrict__ eidx, int* meta) {
  const int p = blockIdx.x * 256 + threadIdx.x;
  if (p < NP) atomicAdd(&meta[eidx[p] & 7], 1);
}

__global__ void k_scan(int* meta) {
  if (threadIdx.x == 0 && blockIdx.x == 0) {
    int off = 0;
    for (int e = 0; e < NE; ++e) {
      meta[16 + e] = off;
      off += ((meta[e] + 127) >> 7) << 7;   // pad each expert's range to x128
    }
    meta[24] = off;
  }
}

__global__ void k_fill(const int* __restrict__ eidx, const float* __restrict__ ew,
                       int* meta, int* slot_token, float* slot_weight) {
  const int p = blockIdx.x * 256 + threadIdx.x;
  if (p < NP) {
    const int e = eidx[p] & 7;
    const int pos = meta[16 + e] + atomicAdd(&meta[8 + e], 1);
    slot_token[pos]  = p >> 1;
    slot_weight[pos] = ew[p];
  }
}

// gather selected token rows -> bf16, zeros for padding slots
__global__ void k_gather(const float* __restrict__ x, const int* __restrict__ slot_token,
                         u16* __restrict__ Xg) {
  const int s = blockIdx.x;
  const int tok = slot_token[s];
  const int c = threadIdx.x * 4;
  alignas(8) u16 b[4] = {0, 0, 0, 0};
  if (tok >= 0) {
    const float4 v = *reinterpret_cast<const float4*>(x + (size_t)tok * DM + c);
    b[0] = f2bf(v.x); b[1] = f2bf(v.y); b[2] = f2bf(v.z); b[3] = f2bf(v.w);
  }
  *reinterpret_cast<uint2*>(Xg + (size_t)s * DM + c) = *reinterpret_cast<const uint2*>(b);
}

// src [K][N] fp32 -> dst [N][K] bf16 (per-expert via blockIdx.z)
__global__ void k_transpose(const float* __restrict__ src, u16* __restrict__ dst, int K, int N) {
  const size_t mo = (size_t)blockIdx.z * K * N;
  const float* s = src + mo;
  u16* d = dst + mo;
  const int n0 = blockIdx.x * 64, k0 = blockIdx.y * 64;
  __shared__ u16 tile[64][72];
  const int t = threadIdx.x;
  const int r = t >> 4, cb = (t & 15) * 4;
#pragma unroll
  for (int it = 0; it < 4; ++it) {
    const float4 v = *reinterpret_cast<const float4*>(s + (size_t)(k0 + r + it * 16) * N + n0 + cb);
    tile[r + it * 16][cb + 0] = f2bf(v.x);
    tile[r + it * 16][cb + 1] = f2bf(v.y);
    tile[r + it * 16][cb + 2] = f2bf(v.z);
    tile[r + it * 16][cb + 3] = f2bf(v.w);
  }
  __syncthreads();
  const int nl = t >> 2, ks = (t & 3) * 16;
  alignas(16) u16 vals[16];
#pragma unroll
  for (int j = 0; j < 16; ++j) vals[j] = tile[ks + j][nl];
  u16* dp = d + (size_t)(n0 + nl) * K + k0 + ks;
  *reinterpret_cast<uint4*>(dp)     = *reinterpret_cast<const uint4*>(vals);
  *reinterpret_cast<uint4*>(dp + 8) = *reinterpret_cast<const uint4*>(vals + 8);
}

// GEMM1: H = silu(Xg @ w1^T') * (Xg @ w2^T')   tiles 128x128, BK=32, dual accumulators
__global__ __launch_bounds__(256, 2)
void k_gemm1(const u16* __restrict__ Xg, const u16* __restrict__ w1T, const u16* __restrict__ w2T,
             u16* __restrict__ H, const int* __restrict__ meta) {
  const int e = blockIdx.z;
  const int cnt = meta[e];
  const int mt = blockIdx.y;
  if (mt * 128 >= cnt) return;
  const int base = meta[16 + e];
  const int n0 = blockIdx.x * 128;

  __shared__ __align__(16) u16 lA[128 * 32];
  __shared__ __align__(16) u16 lB1[128 * 32];
  __shared__ __align__(16) u16 lB2[128 * 32];

  const int tid = threadIdx.x;
  const int lane = tid & 63;
  const int w = tid >> 6;
  const int wr = w >> 1, wc = w & 1;
  const int lrow = lane & 15, lk = lane >> 4;
  const int srow = tid >> 2;
  const int scolb = (tid & 3) * 16;

  const char* Ag  = (const char*)(Xg + (size_t)(base + mt * 128) * DM);
  const char* B1g = (const char*)(w1T + ((size_t)e * DF + n0) * DM);
  const char* B2g = (const char*)(w2T + ((size_t)e * DF + n0) * DM);
  char* lAc = (char*)lA; char* lB1c = (char*)lB1; char* lB2c = (char*)lB2;

  f32x4 acc1[4][4] = {};
  f32x4 acc2[4][4] = {};

  for (int k0 = 0; k0 < DM; k0 += 32) {
    __syncthreads();
    const int kb = k0 * 2;
#pragma unroll
    for (int j = 0; j < 2; ++j) {
      const size_t goff = (size_t)(srow + j * 64) * (DM * 2) + kb + scolb;
      const int loff = w * 1024 + j * 4096;
      gload16(Ag + goff,  lAc + loff);
      gload16(B1g + goff, lB1c + loff);
      gload16(B2g + goff, lB2c + loff);
    }
    asm volatile("s_waitcnt vmcnt(0)" ::: "memory");
    __syncthreads();

    bf16x8 a[4], b1[4], b2[4];
#pragma unroll
    for (int m = 0; m < 4; ++m)
      a[m] = __builtin_bit_cast(bf16x8, *(const u16x8*)(lAc + ((wr * 64 + m * 16 + lrow) * 64 + lk * 16)));
#pragma unroll
    for (int n = 0; n < 4; ++n) {
      b1[n] = __builtin_bit_cast(bf16x8, *(const u16x8*)(lB1c + ((wc * 64 + n * 16 + lrow) * 64 + lk * 16)));
      b2[n] = __builtin_bit_cast(bf16x8, *(const u16x8*)(lB2c + ((wc * 64 + n * 16 + lrow) * 64 + lk * 16)));
    }
#pragma unroll
    for (int m = 0; m < 4; ++m)
#pragma unroll
      for (int n = 0; n < 4; ++n) {
        acc1[m][n] = __builtin_amdgcn_mfma_f32_16x16x32_bf16(a[m], b1[n], acc1[m][n], 0, 0, 0);
        acc2[m][n] = __builtin_amdgcn_mfma_f32_16x16x32_bf16(a[m], b2[n], acc2[m][n], 0, 0, 0);
      }
  }

  u16* Hrow = H + (size_t)(base + mt * 128) * DF + n0;
#pragma unroll
  for (int m = 0; m < 4; ++m)
#pragma unroll
    for (int r = 0; r < 4; ++r) {
      const int rloc = wr * 64 + m * 16 + lk * 4 + r;
      u16* hp = Hrow + (size_t)rloc * DF + wc * 64 + lrow;
#pragma unroll
      for (int n = 0; n < 4; ++n) {
        const float h1 = acc1[m][n][r], h2 = acc2[m][n][r];
        const float sv = h1 / (1.f + __expf(-h1)) * h2;   // silu(h1)*h2
        hp[n * 16] = f2bf(sv);
      }
    }
}

// GEMM2: out[token] += wgt * (H @ w3^T')   tiles 128x128, BK=32, atomic scatter
__global__ __launch_bounds__(256, 2)
void k_gemm2(const u16* __restrict__ H, const u16* __restrict__ w3T, const int* __restrict__ meta,
             const int* __restrict__ slot_token, const float* __restrict__ slot_weight,
             float* __restrict__ out) {
  const int e = blockIdx.z;
  const int cnt = meta[e];
  const int mt = blockIdx.y;
  if (mt * 128 >= cnt) return;
  const int base = meta[16 + e];
  const int n0 = blockIdx.x * 128;

  __shared__ __align__(16) u16 lA[128 * 32];
  __shared__ __align__(16) u16 lB[128 * 32];

  const int tid = threadIdx.x;
  const int lane = tid & 63;
  const int w = tid >> 6;
  const int wr = w >> 1, wc = w & 1;
  const int lrow = lane & 15, lk = lane >> 4;
  const int srow = tid >> 2;
  const int scolb = (tid & 3) * 16;

  const char* Ag = (const char*)(H + (size_t)(base + mt * 128) * DF);
  const char* Bg = (const char*)(w3T + ((size_t)e * DM + n0) * DF);
  char* lAc = (char*)lA; char* lBc = (char*)lB;

  f32x4 acc[4][4] = {};

  for (int k0 = 0; k0 < DF; k0 += 32) {
    __syncthreads();
    const int kb = k0 * 2;
#pragma unroll
    for (int j = 0; j < 2; ++j) {
      const size_t goff = (size_t)(srow + j * 64) * (DF * 2) + kb + scolb;
      const int loff = w * 1024 + j * 4096;
      gload16(Ag + goff, lAc + loff);
      gload16(Bg + goff, lBc + loff);
    }
    asm volatile("s_waitcnt vmcnt(0)" ::: "memory");
    __syncthreads();

    bf16x8 a[4], b[4];
#pragma unroll
    for (int m = 0; m < 4; ++m)
      a[m] = __builtin_bit_cast(bf16x8, *(const u16x8*)(lAc + ((wr * 64 + m * 16 + lrow) * 64 + lk * 16)));
#pragma unroll
    for (int n = 0; n < 4; ++n)
      b[n] = __builtin_bit_cast(bf16x8, *(const u16x8*)(lBc + ((wc * 64 + n * 16 + lrow) * 64 + lk * 16)));
#pragma unroll
    for (int m = 0; m < 4; ++m)
#pragma unroll
      for (int n = 0; n < 4; ++n)
        acc[m][n] = __builtin_amdgcn_mfma_f32_16x16x32_bf16(a[m], b[n], acc[m][n], 0, 0, 0);
  }

  const int sb = base + mt * 128;
#pragma unroll
  for (int m = 0; m < 4; ++m)
#pragma unroll
    for (int r = 0; r < 4; ++r) {
      const int rloc = wr * 64 + m * 16 + lk * 4 + r;
      const int tok = slot_token[sb + rloc];
      const float wgt = slot_weight[sb + rloc];
      if (tok >= 0) {
        float* op = out + (size_t)tok * DM + n0 + wc * 64 + lrow;
#pragma unroll
        for (int n = 0; n < 4; ++n)
          atomicAdd(op + n * 16, wgt * acc[m][n][r]);
      }
    }
}

extern "C" void kernel_launch(void* const* d_in, const int* in_sizes, int n_in,
                              void* d_out, int out_size, void* d_ws, size_t ws_size,
                              hipStream_t stream) {
  const float* x  = (const float*)d_in[0];
  const int* eidx = (const int*)d_in[1];
  const float* ew = (const float*)d_in[2];
  const float* w1 = (const float*)d_in[3];
  const float* w2 = (const float*)d_in[4];
  const float* w3 = (const float*)d_in[5];
  float* out = (float*)d_out;
  char* ws = (char*)d_ws;

  int* meta          = (int*)ws;
  int* slot_token    = (int*)(ws + 256);
  float* slot_weight = (float*)(ws + 256 + (size_t)MAXS * 4);
  size_t off = 256 + (size_t)MAXS * 8;
  u16* Xg  = (u16*)(ws + off); off += (size_t)MAXS * DM * 2;
  u16* w1T = (u16*)(ws + off); off += (size_t)NE * DM * DF * 2;
  u16* w2T = (u16*)(ws + off); off += (size_t)NE * DM * DF * 2;
  u16* w3T = (u16*)(ws + off); off += (size_t)NE * DM * DF * 2;
  u16* H   = (u16*)(ws + off);  // MAXS * DF * 2 bytes

  hipMemsetAsync(d_out, 0, (size_t)NT * DM * 4, stream);
  k_init<<<(MAXS + 255) / 256, 256, 0, stream>>>(meta, slot_token);
  k_count<<<NP / 256, 256, 0, stream>>>(eidx, meta);
  k_scan<<<1, 64, 0, stream>>>(meta);
  k_fill<<<NP / 256, 256, 0, stream>>>(eidx, ew, meta, slot_token, slot_weight);
  k_gather<<<MAXS, 256, 0, stream>>>(x, slot_token, Xg);
  k_transpose<<<dim3(DF / 64, DM / 64, NE), 256, 0, stream>>>(w1, w1T, DM, DF);
  k_transpose<<<dim3(DF / 64, DM / 64, NE), 256, 0, stream>>>(w2, w2T, DM, DF);
  k_transpose<<<dim3(DM / 64, DF / 64, NE), 256, 0, stream>>>(w3, w3T, DF, DM);
  k_gemm1<<<dim3(DF / 128, 128, NE), 256, 0, stream>>>(Xg, w1T, w2T, H, meta);
  k_gemm2<<<dim3(DM / 128, 128, NE), 256, 0, stream>>>(H, w3T, meta, slot_token, slot_weight, out);
}

// Round 2
// 566.157 us; speedup vs baseline: 1.0381x; 1.0381x over previous
//
#include <hip/hip_runtime.h>
#include <cstdint>

typedef unsigned short u16;
typedef u16 u16x8 __attribute__((ext_vector_type(8)));
typedef __bf16 bf16x8 __attribute__((ext_vector_type(8)));
typedef float f32x4 __attribute__((ext_vector_type(4)));

#define DEV static __device__ __forceinline__

// problem constants
constexpr int NT = 8192;         // tokens
constexpr int NP = NT * 2;       // 16384 (token, k) pairs
constexpr int NE = 8;
constexpr int DM = 1024;
constexpr int DF = 2048;
constexpr int MAXS = 17408;      // >= 16384 + 8*127 alignment slack
constexpr int MAXTILES = 136;    // >= 128 + 7 (sum of per-expert ceil)

DEV u16 f2bf(float f) {          // RTNE float -> bf16 bits
  uint32_t u = __builtin_bit_cast(uint32_t, f);
  u += 0x7fffu + ((u >> 16) & 1u);
  return (u16)(u >> 16);
}

DEV void gload16(const void* g, void* l) {
  __builtin_amdgcn_global_load_lds((const __attribute__((address_space(1))) void*)g,
                                   (__attribute__((address_space(3))) void*)l, 16, 0, 0);
}

// ---- routing ----
// meta[0..7]=counts, [8..15]=cursor, [16..23]=padded offsets, [24]=total rows,
// [25]=num tiles, [32..32+MAXTILES)=tile table (expert | mtile<<8)
__global__ void k_init(int* meta, int* slot_token) {
  const int i = blockIdx.x * 256 + threadIdx.x;
  if (i < 32) meta[i] = 0;
  if (i < MAXS) slot_token[i] = -1;
}

__global__ void k_count(const int* __restrict__ eidx, int* meta) {
  const int p = blockIdx.x * 256 + threadIdx.x;
  if (p < NP) atomicAdd(&meta[eidx[p] & 7], 1);
}

__global__ void k_scan(int* meta) {
  if (threadIdx.x == 0 && blockIdx.x == 0) {
    int off = 0, ti = 0;
    for (int e = 0; e < NE; ++e) {
      meta[16 + e] = off;
      const int c = meta[e];
      off += ((c + 127) >> 7) << 7;
      for (int mt = 0; mt * 128 < c; ++mt) meta[32 + ti++] = e | (mt << 8);
    }
    meta[24] = off;
    meta[25] = ti;
  }
}

__global__ void k_fill(const int* __restrict__ eidx, const float* __restrict__ ew,
                       int* meta, int* slot_token, float* slot_weight) {
  const int p = blockIdx.x * 256 + threadIdx.x;
  if (p < NP) {
    const int e = eidx[p] & 7;
    const int pos = meta[16 + e] + atomicAdd(&meta[8 + e], 1);
    slot_token[pos]  = p >> 1;
    slot_weight[pos] = ew[p];
  }
}

// gather selected token rows -> bf16, zeros for padding slots
__global__ void k_gather(const float* __restrict__ x, const int* __restrict__ slot_token,
                         u16* __restrict__ Xg) {
  const int s = blockIdx.x;
  const int tok = slot_token[s];
  const int c = threadIdx.x * 4;
  alignas(8) u16 b[4] = {0, 0, 0, 0};
  if (tok >= 0) {
    const float4 v = *reinterpret_cast<const float4*>(x + (size_t)tok * DM + c);
    b[0] = f2bf(v.x); b[1] = f2bf(v.y); b[2] = f2bf(v.z); b[3] = f2bf(v.w);
  }
  *reinterpret_cast<uint2*>(Xg + (size_t)s * DM + c) = *reinterpret_cast<const uint2*>(b);
}

// src [K][N] fp32 -> dst [N][K] bf16 (per-expert via blockIdx.z)
__global__ void k_transpose(const float* __restrict__ src, u16* __restrict__ dst, int K, int N) {
  const size_t mo = (size_t)blockIdx.z * K * N;
  const float* s = src + mo;
  u16* d = dst + mo;
  const int n0 = blockIdx.x * 64, k0 = blockIdx.y * 64;
  __shared__ u16 tile[64][72];
  const int t = threadIdx.x;
  const int r = t >> 4, cb = (t & 15) * 4;
#pragma unroll
  for (int it = 0; it < 4; ++it) {
    const float4 v = *reinterpret_cast<const float4*>(s + (size_t)(k0 + r + it * 16) * N + n0 + cb);
    tile[r + it * 16][cb + 0] = f2bf(v.x);
    tile[r + it * 16][cb + 1] = f2bf(v.y);
    tile[r + it * 16][cb + 2] = f2bf(v.z);
    tile[r + it * 16][cb + 3] = f2bf(v.w);
  }
  __syncthreads();
  const int nl = t >> 2, ks = (t & 3) * 16;
  alignas(16) u16 vals[16];
#pragma unroll
  for (int j = 0; j < 16; ++j) vals[j] = tile[ks + j][nl];
  u16* dp = d + (size_t)(n0 + nl) * K + k0 + ks;
  *reinterpret_cast<uint4*>(dp)     = *reinterpret_cast<const uint4*>(vals);
  *reinterpret_cast<uint4*>(dp + 8) = *reinterpret_cast<const uint4*>(vals + 8);
}

// GEMM1: H = silu(Xg @ w1^T') * (Xg @ w2^T')
// tile 128x64, BK=32, 2-phase prefetch, per-wave 64x32 dual (64 AGPR)
__global__ __launch_bounds__(256, 3)
void k_gemm1(const u16* __restrict__ Xg, const u16* __restrict__ w1T, const u16* __restrict__ w2T,
             u16* __restrict__ H, const int* __restrict__ meta) {
  const int ti = blockIdx.y;
  if (ti >= meta[25]) return;
  const int ent = meta[32 + ti];
  const int e = ent & 255, mt = ent >> 8;
  const int base = meta[16 + e];
  const int n0 = blockIdx.x * 64;

  // per buffer: A[128][32] @0 (8KB) | B1[64][32] @8192 (4KB) | B2[64][32] @12288 (4KB)
  __shared__ __align__(16) char sm[2][16384];

  const int tid = threadIdx.x;
  const int lane = tid & 63;
  const int w = tid >> 6;
  const int wr = w >> 1, wc = w & 1;
  const int lrow = lane & 15, lk = lane >> 4;
  const int srow = tid >> 2;
  const int scolb = (tid & 3) * 16;

  const char* Ag  = (const char*)(Xg + (size_t)(base + mt * 128) * DM);
  const char* B1g = (const char*)(w1T + ((size_t)e * DF + n0) * DM);
  const char* B2g = (const char*)(w2T + ((size_t)e * DF + n0) * DM);

  f32x4 acc1[4][2] = {};
  f32x4 acc2[4][2] = {};

  auto STAGE = [&](int buf, int k0) {
    const int kb = k0 * 2;
    char* s = sm[buf];
    gload16(Ag  + (size_t)srow * 2048 + kb + scolb,        s + w * 1024);
    gload16(Ag  + (size_t)(srow + 64) * 2048 + kb + scolb, s + 4096 + w * 1024);
    gload16(B1g + (size_t)srow * 2048 + kb + scolb,        s + 8192 + w * 1024);
    gload16(B2g + (size_t)srow * 2048 + kb + scolb,        s + 12288 + w * 1024);
  };

  STAGE(0, 0);
  asm volatile("s_waitcnt vmcnt(0)" ::: "memory");
  __syncthreads();

  int cur = 0;
  for (int k0 = 0; k0 < DM; k0 += 32) {
    if (k0 + 32 < DM) STAGE(cur ^ 1, k0 + 32);   // prefetch next tile; lands during MFMA
    const char* s = sm[cur];
    bf16x8 a[4], b1[2], b2[2];
#pragma unroll
    for (int m = 0; m < 4; ++m)
      a[m] = __builtin_bit_cast(bf16x8, *(const u16x8*)(s + ((wr * 64 + m * 16 + lrow) * 64 + lk * 16)));
#pragma unroll
    for (int n = 0; n < 2; ++n) {
      b1[n] = __builtin_bit_cast(bf16x8, *(const u16x8*)(s + 8192  + (wc * 32 + n * 16 + lrow) * 64 + lk * 16));
      b2[n] = __builtin_bit_cast(bf16x8, *(const u16x8*)(s + 12288 + (wc * 32 + n * 16 + lrow) * 64 + lk * 16));
    }
#pragma unroll
    for (int m = 0; m < 4; ++m)
#pragma unroll
      for (int n = 0; n < 2; ++n) {
        acc1[m][n] = __builtin_amdgcn_mfma_f32_16x16x32_bf16(a[m], b1[n], acc1[m][n], 0, 0, 0);
        acc2[m][n] = __builtin_amdgcn_mfma_f32_16x16x32_bf16(a[m], b2[n], acc2[m][n], 0, 0, 0);
      }
    asm volatile("s_waitcnt vmcnt(0)" ::: "memory");
    __syncthreads();
    cur ^= 1;
  }

  u16* Hrow = H + (size_t)(base + mt * 128) * DF + n0;
#pragma unroll
  for (int m = 0; m < 4; ++m)
#pragma unroll
    for (int r = 0; r < 4; ++r) {
      const int rl = wr * 64 + m * 16 + lk * 4 + r;
      u16* hp = Hrow + (size_t)rl * DF + wc * 32 + lrow;
#pragma unroll
      for (int n = 0; n < 2; ++n) {
        const float h1 = acc1[m][n][r], h2 = acc2[m][n][r];
        const float sv = h1 / (1.f + __expf(-h1)) * h2;   // silu(h1)*h2
        hp[n * 16] = f2bf(sv);
      }
    }
}

// GEMM2: out[token] += wgt * (H @ w3^T')
// tile 128x64, BK=32, 2-phase prefetch, per-wave 64x32 (32 AGPR)
__global__ __launch_bounds__(256, 4)
void k_gemm2(const u16* __restrict__ H, const u16* __restrict__ w3T, const int* __restrict__ meta,
             const int* __restrict__ slot_token, const float* __restrict__ slot_weight,
             float* __restrict__ out) {
  const int ti = blockIdx.y;
  if (ti >= meta[25]) return;
  const int ent = meta[32 + ti];
  const int e = ent & 255, mt = ent >> 8;
  const int base = meta[16 + e];
  const int n0 = blockIdx.x * 64;

  // per buffer: A[128][32] @0 (8KB) | B[64][32] @8192 (4KB)
  __shared__ __align__(16) char sm[2][12288];

  const int tid = threadIdx.x;
  const int lane = tid & 63;
  const int w = tid >> 6;
  const int wr = w >> 1, wc = w & 1;
  const int lrow = lane & 15, lk = lane >> 4;
  const int srow = tid >> 2;
  const int scolb = (tid & 3) * 16;

  const char* Ag = (const char*)(H + (size_t)(base + mt * 128) * DF);
  const char* Bg = (const char*)(w3T + ((size_t)e * DM + n0) * DF);

  f32x4 acc[4][2] = {};

  auto STAGE = [&](int buf, int k0) {
    const int kb = k0 * 2;
    char* s = sm[buf];
    gload16(Ag + (size_t)srow * 4096 + kb + scolb,        s + w * 1024);
    gload16(Ag + (size_t)(srow + 64) * 4096 + kb + scolb, s + 4096 + w * 1024);
    gload16(Bg + (size_t)srow * 4096 + kb + scolb,        s + 8192 + w * 1024);
  };

  STAGE(0, 0);
  asm volatile("s_waitcnt vmcnt(0)" ::: "memory");
  __syncthreads();

  int cur = 0;
  for (int k0 = 0; k0 < DF; k0 += 32) {
    if (k0 + 32 < DF) STAGE(cur ^ 1, k0 + 32);
    const char* s = sm[cur];
    bf16x8 a[4], b[2];
#pragma unroll
    for (int m = 0; m < 4; ++m)
      a[m] = __builtin_bit_cast(bf16x8, *(const u16x8*)(s + ((wr * 64 + m * 16 + lrow) * 64 + lk * 16)));
#pragma unroll
    for (int n = 0; n < 2; ++n)
      b[n] = __builtin_bit_cast(bf16x8, *(const u16x8*)(s + 8192 + (wc * 32 + n * 16 + lrow) * 64 + lk * 16));
#pragma unroll
    for (int m = 0; m < 4; ++m)
#pragma unroll
      for (int n = 0; n < 2; ++n)
        acc[m][n] = __builtin_amdgcn_mfma_f32_16x16x32_bf16(a[m], b[n], acc[m][n], 0, 0, 0);
    asm volatile("s_waitcnt vmcnt(0)" ::: "memory");
    __syncthreads();
    cur ^= 1;
  }

  const int sb = base + mt * 128;
#pragma unroll
  for (int m = 0; m < 4; ++m)
#pragma unroll
    for (int r = 0; r < 4; ++r) {
      const int rl = wr * 64 + m * 16 + lk * 4 + r;
      const int tok = slot_token[sb + rl];
      const float wgt = slot_weight[sb + rl];
      if (tok >= 0) {
        float* op = out + (size_t)tok * DM + n0 + wc * 32 + lrow;
#pragma unroll
        for (int n = 0; n < 2; ++n)
          atomicAdd(op + n * 16, wgt * acc[m][n][r]);
      }
    }
}

extern "C" void kernel_launch(void* const* d_in, const int* in_sizes, int n_in,
                              void* d_out, int out_size, void* d_ws, size_t ws_size,
                              hipStream_t stream) {
  const float* x  = (const float*)d_in[0];
  const int* eidx = (const int*)d_in[1];
  const float* ew = (const float*)d_in[2];
  const float* w1 = (const float*)d_in[3];
  const float* w2 = (const float*)d_in[4];
  const float* w3 = (const float*)d_in[5];
  float* out = (float*)d_out;
  char* ws = (char*)d_ws;

  int* meta          = (int*)ws;                       // 1024 bytes (incl. tile table)
  int* slot_token    = (int*)(ws + 1024);
  float* slot_weight = (float*)(ws + 1024 + (size_t)MAXS * 4);
  size_t off = 1024 + (size_t)MAXS * 8;
  u16* Xg  = (u16*)(ws + off); off += (size_t)MAXS * DM * 2;
  u16* w1T = (u16*)(ws + off); off += (size_t)NE * DM * DF * 2;
  u16* w2T = (u16*)(ws + off); off += (size_t)NE * DM * DF * 2;
  u16* w3T = (u16*)(ws + off); off += (size_t)NE * DM * DF * 2;
  u16* H   = (u16*)(ws + off);  // MAXS * DF * 2 bytes

  hipMemsetAsync(d_out, 0, (size_t)NT * DM * 4, stream);
  k_init<<<(MAXS + 255) / 256, 256, 0, stream>>>(meta, slot_token);
  k_count<<<NP / 256, 256, 0, stream>>>(eidx, meta);
  k_scan<<<1, 64, 0, stream>>>(meta);
  k_fill<<<NP / 256, 256, 0, stream>>>(eidx, ew, meta, slot_token, slot_weight);
  k_gather<<<MAXS, 256, 0, stream>>>(x, slot_token, Xg);
  k_transpose<<<dim3(DF / 64, DM / 64, NE), 256, 0, stream>>>(w1, w1T, DM, DF);
  k_transpose<<<dim3(DF / 64, DM / 64, NE), 256, 0, stream>>>(w2, w2T, DM, DF);
  k_transpose<<<dim3(DM / 64, DF / 64, NE), 256, 0, stream>>>(w3, w3T, DF, DM);
  k_gemm1<<<dim3(DF / 64, MAXTILES, 1), 256, 0, stream>>>(Xg, w1T, w2T, H, meta);
  k_gemm2<<<dim3(DM / 64, MAXTILES, 1), 256, 0, stream>>>(H, w3T, meta, slot_token, slot_weight, out);
}